// Round 1
// baseline (232.804 us; speedup 1.0000x reference)
//
#include <hip/hip_runtime.h>
#include <hip/hip_bf16.h>

#define BB   64
#define NTOT 800000
#define NF4  200000          // NTOT / 4
#define NP   128
#define NH1  256
#define NH2  128
#define NC   32
#define EPSV 1e-5f

// ---------------------------------------------------------------------------
// Scatter-reduce: WX[b, idx[n]] += x[b,n] * w[n]
// idx is sorted -> exploit wave-uniform pathway for shuffle-reduce + 1 atomic.
// ---------------------------------------------------------------------------
__global__ __launch_bounds__(256) void k_scatter(
    const float* __restrict__ x, const float* __restrict__ w,
    const int* __restrict__ idx, float* __restrict__ WX)
{
    const int n4  = blockIdx.x * 256 + threadIdx.x;   // float4 index
    const bool act = (n4 < NF4);
    const unsigned long long amask = __ballot(act ? 1 : 0);
    if (amask == 0ull) return;                        // fully-inactive wave

    float4 wv = make_float4(0.f, 0.f, 0.f, 0.f);
    int4   pv = make_int4(0, 0, 0, 0);
    if (act) {
        wv = reinterpret_cast<const float4*>(w)[n4];
        pv = reinterpret_cast<const int4*>(idx)[n4];
    }
    const bool uni_t = (pv.x == pv.w);                // sorted -> all 4 equal
    const int  fp    = __builtin_amdgcn_readfirstlane(pv.x);
    const bool wave_uni =
        (__ballot((act && uni_t && (pv.x == fp)) ? 1 : 0) == ~0ull);
    if (!act) return;                                 // (never mixed: NF4 % 64 == 0)

    const int lane = threadIdx.x & 63;
    const float4* __restrict__ xv = reinterpret_cast<const float4*>(x);

    for (int b = 0; b < BB; b += 8) {
        float4 xr[8];
        #pragma unroll
        for (int i = 0; i < 8; ++i)
            xr[i] = xv[(b + i) * NF4 + n4];           // coalesced 16B/lane

        float s[8];
        #pragma unroll
        for (int i = 0; i < 8; ++i)
            s[i] = fmaf(xr[i].x, wv.x, fmaf(xr[i].y, wv.y,
                   fmaf(xr[i].z, wv.z, xr[i].w * wv.w)));

        if (wave_uni) {
            #pragma unroll
            for (int i = 0; i < 8; ++i) {
                float v = s[i];
                #pragma unroll
                for (int off = 32; off > 0; off >>= 1)
                    v += __shfl_xor(v, off);
                if (lane == 0) atomicAdd(&WX[(b + i) * NP + fp], v);
            }
        } else {  // pathway boundary inside this wave (rare: ~127/3125 waves)
            #pragma unroll
            for (int i = 0; i < 8; ++i) {
                if (uni_t) {
                    atomicAdd(&WX[(b + i) * NP + pv.x], s[i]);
                } else {
                    atomicAdd(&WX[(b + i) * NP + pv.x], xr[i].x * wv.x);
                    atomicAdd(&WX[(b + i) * NP + pv.y], xr[i].y * wv.y);
                    atomicAdd(&WX[(b + i) * NP + pv.z], xr[i].z * wv.z);
                    atomicAdd(&WX[(b + i) * NP + pv.w], xr[i].w * wv.w);
                }
            }
        }
    }
}

// ---------------------------------------------------------------------------
// BN0 (batch stats over axis 0) + CancelOut sigmoid gate. One block, 128 thr.
// ---------------------------------------------------------------------------
__global__ void k_bn0(const float* __restrict__ WX,
                      const float* __restrict__ co_w,
                      const float* __restrict__ g,
                      const float* __restrict__ beta,
                      float* __restrict__ Z)
{
    const int p = threadIdx.x;  // 0..127
    float sum = 0.f, sq = 0.f;
    for (int b = 0; b < BB; ++b) {
        float r = fmaxf(WX[b * NP + p], 0.f);
        sum += r; sq += r * r;
    }
    const float m   = sum * (1.f / BB);
    const float var = sq * (1.f / BB) - m * m;
    const float sc  = rsqrtf(var + EPSV) * g[p];
    const float bt  = beta[p];
    const float sig = 1.f / (1.f + expf(-co_w[p]));
    for (int b = 0; b < BB; ++b) {
        float r = fmaxf(WX[b * NP + p], 0.f);
        Z[b * NP + p] = ((r - m) * sc + bt) * sig;
    }
}

// ---------------------------------------------------------------------------
// Linear -> ReLU -> BN(batch stats). One block per output column j,
// 64 threads = 1 wave = the batch dim -> BN stats via wave shuffle.
// ---------------------------------------------------------------------------
template <int K, int NOUT>
__global__ void k_fc_bn(const float* __restrict__ in,    // [BB, K]
                        const float* __restrict__ W,     // [K, NOUT]
                        const float* __restrict__ bias,
                        const float* __restrict__ g,
                        const float* __restrict__ beta,
                        float* __restrict__ out)         // [BB, NOUT]
{
    const int j = blockIdx.x;
    const int b = threadIdx.x;  // 0..63
    const float* __restrict__ row = in + b * K;
    float acc = bias[j];
    #pragma unroll 8
    for (int k = 0; k < K; ++k)
        acc = fmaf(row[k], W[k * NOUT + j], acc);
    acc = fmaxf(acc, 0.f);
    float s = acc, q = acc * acc;
    #pragma unroll
    for (int off = 32; off > 0; off >>= 1) {
        s += __shfl_xor(s, off);
        q += __shfl_xor(q, off);
    }
    const float m   = s * (1.f / BB);
    const float var = q * (1.f / BB) - m * m;
    out[b * NOUT + j] = (acc - m) * rsqrtf(var + EPSV) * g[j] + beta[j];
}

// ---------------------------------------------------------------------------
// Final Linear + row softmax. One block per batch row, 32 threads = classes.
// ---------------------------------------------------------------------------
__global__ void k_head(const float* __restrict__ h,   // [BB, NH2]
                       const float* __restrict__ Wo,  // [NH2, NC]
                       const float* __restrict__ bo,
                       float* __restrict__ y)         // [BB, NC]
{
    const int b = blockIdx.x;
    const int c = threadIdx.x;  // 0..31
    const float* __restrict__ row = h + b * NH2;
    float acc = bo[c];
    #pragma unroll 8
    for (int k = 0; k < NH2; ++k)
        acc = fmaf(row[k], Wo[k * NC + c], acc);
    float mx = acc;
    #pragma unroll
    for (int off = 16; off > 0; off >>= 1)
        mx = fmaxf(mx, __shfl_xor(mx, off));
    const float e = expf(acc - mx);
    float s = e;
    #pragma unroll
    for (int off = 16; off > 0; off >>= 1)
        s += __shfl_xor(s, off);
    y[b * NC + c] = e / s;
}

// ---------------------------------------------------------------------------
extern "C" void kernel_launch(void* const* d_in, const int* in_sizes, int n_in,
                              void* d_out, int out_size, void* d_ws, size_t ws_size,
                              hipStream_t stream)
{
    const float* x    = (const float*)d_in[0];
    const float* w    = (const float*)d_in[1];
    const float* co_w = (const float*)d_in[2];
    const float* bn0g = (const float*)d_in[3];
    const float* bn0b = (const float*)d_in[4];
    const float* W1   = (const float*)d_in[5];
    const float* b1   = (const float*)d_in[6];
    const float* bn1g = (const float*)d_in[7];
    const float* bn1b = (const float*)d_in[8];
    const float* W2   = (const float*)d_in[9];
    const float* b2   = (const float*)d_in[10];
    const float* bn2g = (const float*)d_in[11];
    const float* bn2b = (const float*)d_in[12];
    const float* Wo   = (const float*)d_in[13];
    const float* bo   = (const float*)d_in[14];
    const int*   idx  = (const int*)d_in[15];

    float* out = (float*)d_out;
    float* y   = out;               // [64, 32]  (output 0)
    float* Z   = out + BB * NC;     // [64, 128] (output 1)

    float* WX = (float*)d_ws;       // 8192 f32
    float* h1 = WX + BB * NP;       // 16384 f32
    float* h2 = h1 + BB * NH1;      // 8192 f32

    hipMemsetAsync(WX, 0, BB * NP * sizeof(float), stream);
    k_scatter<<<(NF4 + 255) / 256, 256, 0, stream>>>(x, w, idx, WX);
    k_bn0<<<1, NP, 0, stream>>>(WX, co_w, bn0g, bn0b, Z);
    k_fc_bn<NP, NH1><<<NH1, BB, 0, stream>>>(Z, W1, b1, bn1g, bn1b, h1);
    k_fc_bn<NH1, NH2><<<NH2, BB, 0, stream>>>(h1, W2, b2, bn2g, bn2b, h2);
    k_head<<<BB, NC, 0, stream>>>(h2, Wo, bo, y);
}

// Round 2
// 190.356 us; speedup vs baseline: 1.2230x; 1.2230x over previous
//
#include <hip/hip_runtime.h>
#include <hip/hip_bf16.h>

#define BB   64
#define NTOT 800000
#define NF4  200000          // NTOT / 4
#define NP   128
#define NH1  256
#define NH2  128
#define NC   32
#define EPSV 1e-5f
#define BG   16              // batches per block (batch split 4-ways)

__device__ __forceinline__ int bitrev4(int l) {
    return ((l & 1) << 3) | ((l & 2) << 1) | ((l & 4) >> 1) | ((l & 8) >> 3);
}

template <int C, int M>
__device__ __forceinline__ void red_step(float* v, int lane) {
    const bool hi = (lane & M) != 0;
    #pragma unroll
    for (int j = 0; j < C / 2; ++j) {
        float mine  = hi ? v[j + C / 2] : v[j];
        float other = hi ? v[j]         : v[j + C / 2];
        v[j] = mine + __shfl_xor(other, M);
    }
}

// ---------------------------------------------------------------------------
// Scatter-reduce: WX[b, idx[n]] += x[b,n] * w[n]     (idx sorted)
// blockIdx.x: n4 chunk (256 float4 each). blockIdx.y: 16-batch slice.
// Fast path (wave-uniform pathway): 16 buffered loads -> dot -> 17-shuffle
// transpose-reduce -> ONE end-of-wave atomic per lane 0..15.
// ---------------------------------------------------------------------------
__global__ __launch_bounds__(256, 4) void k_scatter(
    const float* __restrict__ x, const float* __restrict__ w,
    const int* __restrict__ idx, float* __restrict__ WX)
{
    const int n4 = blockIdx.x * 256 + threadIdx.x;   // float4 index
    if (n4 >= NF4) return;                           // NF4 % 64 == 0: whole waves
    const int b0   = blockIdx.y * BG;
    const int lane = threadIdx.x & 63;

    const float4 wv = reinterpret_cast<const float4*>(w)[n4];
    const int4   pv = reinterpret_cast<const int4*>(idx)[n4];

    const bool uni_t = (pv.x == pv.w);               // sorted -> all 4 equal
    const int  fp    = __builtin_amdgcn_readfirstlane(pv.x);
    const bool wave_uni =
        (__ballot((uni_t && (pv.x == fp)) ? 1 : 0) == ~0ull);

    const float4* __restrict__ xv = reinterpret_cast<const float4*>(x);

    if (wave_uni) {
        float4 xr[BG];
        #pragma unroll
        for (int i = 0; i < BG; ++i)                 // 16 independent 16B loads
            xr[i] = xv[(b0 + i) * NF4 + n4];
        float v[BG];
        #pragma unroll
        for (int i = 0; i < BG; ++i)
            v[i] = fmaf(xr[i].x, wv.x, fmaf(xr[i].y, wv.y,
                   fmaf(xr[i].z, wv.z, xr[i].w * wv.w)));
        // 16 values x 64 lanes -> every lane holds full sum of value bitrev4(lane&15)
        red_step<16, 1>(v, lane);
        red_step<8,  2>(v, lane);
        red_step<4,  4>(v, lane);
        red_step<2,  8>(v, lane);
        v[0] += __shfl_xor(v[0], 16);
        v[0] += __shfl_xor(v[0], 32);
        if (lane < 16)
            atomicAdd(&WX[(b0 + bitrev4(lane)) * NP + fp], v[0]);
    } else {  // pathway boundary inside wave: rare (~4% of waves)
        #pragma unroll 4
        for (int i = 0; i < BG; ++i) {
            float4 xr = xv[(b0 + i) * NF4 + n4];
            float* row = &WX[(b0 + i) * NP];
            if (uni_t) {
                float s = fmaf(xr.x, wv.x, fmaf(xr.y, wv.y,
                          fmaf(xr.z, wv.z, xr.w * wv.w)));
                atomicAdd(&row[pv.x], s);
            } else {
                atomicAdd(&row[pv.x], xr.x * wv.x);
                atomicAdd(&row[pv.y], xr.y * wv.y);
                atomicAdd(&row[pv.z], xr.z * wv.z);
                atomicAdd(&row[pv.w], xr.w * wv.w);
            }
        }
    }
}

// ---------------------------------------------------------------------------
// BN0 (batch stats over axis 0) + CancelOut sigmoid gate. One block, 128 thr.
// ---------------------------------------------------------------------------
__global__ void k_bn0(const float* __restrict__ WX,
                      const float* __restrict__ co_w,
                      const float* __restrict__ g,
                      const float* __restrict__ beta,
                      float* __restrict__ Z)
{
    const int p = threadIdx.x;  // 0..127
    float sum = 0.f, sq = 0.f;
    for (int b = 0; b < BB; ++b) {
        float r = fmaxf(WX[b * NP + p], 0.f);
        sum += r; sq += r * r;
    }
    const float m   = sum * (1.f / BB);
    const float var = sq * (1.f / BB) - m * m;
    const float sc  = rsqrtf(var + EPSV) * g[p];
    const float bt  = beta[p];
    const float sig = 1.f / (1.f + expf(-co_w[p]));
    for (int b = 0; b < BB; ++b) {
        float r = fmaxf(WX[b * NP + p], 0.f);
        Z[b * NP + p] = ((r - m) * sc + bt) * sig;
    }
}

// ---------------------------------------------------------------------------
// Linear -> ReLU -> BN(batch stats). One block per output column j,
// 64 threads = 1 wave = the batch dim -> BN stats via wave shuffle.
// ---------------------------------------------------------------------------
template <int K, int NOUT>
__global__ void k_fc_bn(const float* __restrict__ in,    // [BB, K]
                        const float* __restrict__ W,     // [K, NOUT]
                        const float* __restrict__ bias,
                        const float* __restrict__ g,
                        const float* __restrict__ beta,
                        float* __restrict__ out)         // [BB, NOUT]
{
    const int j = blockIdx.x;
    const int b = threadIdx.x;  // 0..63
    const float* __restrict__ row = in + b * K;
    float acc = bias[j];
    #pragma unroll 8
    for (int k = 0; k < K; ++k)
        acc = fmaf(row[k], W[k * NOUT + j], acc);
    acc = fmaxf(acc, 0.f);
    float s = acc, q = acc * acc;
    #pragma unroll
    for (int off = 32; off > 0; off >>= 1) {
        s += __shfl_xor(s, off);
        q += __shfl_xor(q, off);
    }
    const float m   = s * (1.f / BB);
    const float var = q * (1.f / BB) - m * m;
    out[b * NOUT + j] = (acc - m) * rsqrtf(var + EPSV) * g[j] + beta[j];
}

// ---------------------------------------------------------------------------
// Final Linear + row softmax. One block per batch row, 32 threads = classes.
// ---------------------------------------------------------------------------
__global__ void k_head(const float* __restrict__ h,   // [BB, NH2]
                       const float* __restrict__ Wo,  // [NH2, NC]
                       const float* __restrict__ bo,
                       float* __restrict__ y)         // [BB, NC]
{
    const int b = blockIdx.x;
    const int c = threadIdx.x;  // 0..31
    const float* __restrict__ row = h + b * NH2;
    float acc = bo[c];
    #pragma unroll 8
    for (int k = 0; k < NH2; ++k)
        acc = fmaf(row[k], Wo[k * NC + c], acc);
    float mx = acc;
    #pragma unroll
    for (int off = 16; off > 0; off >>= 1)
        mx = fmaxf(mx, __shfl_xor(mx, off));
    const float e = expf(acc - mx);
    float s = e;
    #pragma unroll
    for (int off = 16; off > 0; off >>= 1)
        s += __shfl_xor(s, off);
    y[b * NC + c] = e / s;
}

// ---------------------------------------------------------------------------
extern "C" void kernel_launch(void* const* d_in, const int* in_sizes, int n_in,
                              void* d_out, int out_size, void* d_ws, size_t ws_size,
                              hipStream_t stream)
{
    const float* x    = (const float*)d_in[0];
    const float* w    = (const float*)d_in[1];
    const float* co_w = (const float*)d_in[2];
    const float* bn0g = (const float*)d_in[3];
    const float* bn0b = (const float*)d_in[4];
    const float* W1   = (const float*)d_in[5];
    const float* b1   = (const float*)d_in[6];
    const float* bn1g = (const float*)d_in[7];
    const float* bn1b = (const float*)d_in[8];
    const float* W2   = (const float*)d_in[9];
    const float* b2   = (const float*)d_in[10];
    const float* bn2g = (const float*)d_in[11];
    const float* bn2b = (const float*)d_in[12];
    const float* Wo   = (const float*)d_in[13];
    const float* bo   = (const float*)d_in[14];
    const int*   idx  = (const int*)d_in[15];

    float* out = (float*)d_out;
    float* y   = out;               // [64, 32]  (output 0)
    float* Z   = out + BB * NC;     // [64, 128] (output 1)

    float* WX = (float*)d_ws;       // 8192 f32
    float* h1 = WX + BB * NP;       // 16384 f32
    float* h2 = h1 + BB * NH1;      // 8192 f32

    hipMemsetAsync(WX, 0, BB * NP * sizeof(float), stream);
    dim3 sgrid((NF4 + 255) / 256, BB / BG);
    k_scatter<<<sgrid, 256, 0, stream>>>(x, w, idx, WX);
    k_bn0<<<1, NP, 0, stream>>>(WX, co_w, bn0g, bn0b, Z);
    k_fc_bn<NP, NH1><<<NH1, BB, 0, stream>>>(Z, W1, b1, bn1g, bn1b, h1);
    k_fc_bn<NH1, NH2><<<NH2, BB, 0, stream>>>(h1, W2, b2, bn2g, bn2b, h2);
    k_head<<<BB, NC, 0, stream>>>(h2, Wo, bo, y);
}